// Round 1
// baseline (4448.705 us; speedup 1.0000x reference)
//
#include <hip/hip_runtime.h>

static constexpr int N_ = 32, V_ = 25, T_ = 64, C_ = 256;
static constexpr int S_ = 3, ST_ = 2, CI_ = 64, K_ = 7;
static constexpr int M_  = N_ * V_ * T_;          // 51200 rows (also N*T*V)
static constexpr int TC_ = T_ * C_;               // 16384
static constexpr int VC_ = V_ * C_;               // 6400
static constexpr long TOT_ = (long)M_ * C_;       // 13,107,200

__device__ __forceinline__ float gelu_f(float x) {
    return 0.5f * x * (1.0f + erff(x * 0.70710678118654752f));
}

// ---------------- generic tiled GEMM: Out(M,Nc) = A(M,Kc) @ W(Kc,Nc) (+bias) ---
// W element (k,j) at W[k*ldw + j]  (strided views of Wo_s / Wo_t blocks)
__global__ __launch_bounds__(256) void gemm_bias(
    const float* __restrict__ A, int lda,
    const float* __restrict__ W, int ldw,
    const float* __restrict__ bias,
    float* __restrict__ Out, int M, int Nc, int Kc)
{
    __shared__ float As[64][17];
    __shared__ float Ws[16][65];
    const int tid = threadIdx.x;
    const int tx = tid & 15, ty = tid >> 4;
    const int row0 = blockIdx.y * 64, col0 = blockIdx.x * 64;
    float acc[4][4] = {};
    for (int k0 = 0; k0 < Kc; k0 += 16) {
        for (int l = tid; l < 64 * 16; l += 256) {
            int r = l >> 4, c = l & 15;
            As[r][c] = A[(long)(row0 + r) * lda + k0 + c];
        }
        for (int l = tid; l < 16 * 64; l += 256) {
            int r = l >> 6, c = l & 63;
            Ws[r][c] = W[(long)(k0 + r) * ldw + col0 + c];
        }
        __syncthreads();
        #pragma unroll
        for (int kk = 0; kk < 16; ++kk) {
            float a[4], w[4];
            #pragma unroll
            for (int i = 0; i < 4; ++i) a[i] = As[ty * 4 + i][kk];
            #pragma unroll
            for (int j = 0; j < 4; ++j) w[j] = Ws[kk][tx * 4 + j];
            #pragma unroll
            for (int i = 0; i < 4; ++i)
                #pragma unroll
                for (int j = 0; j < 4; ++j) acc[i][j] += a[i] * w[j];
        }
        __syncthreads();
    }
    for (int i = 0; i < 4; ++i) {
        long r = row0 + ty * 4 + i;
        for (int j = 0; j < 4; ++j) {
            int c = col0 + tx * 4 + j;
            float b = bias ? bias[c] : 0.0f;
            Out[r * Nc + c] = acc[i][j] + b;
        }
    }
}

// ---------------- small utility kernels ---------------------------------------
__global__ void zero_f32(float* __restrict__ p, int n) {
    int i = blockIdx.x * 256 + threadIdx.x;
    if (i < n) p[i] = 0.0f;
}
__global__ void bcast_bias(const float* __restrict__ b, float* __restrict__ P, int total) {
    int i = blockIdx.x * 256 + threadIdx.x;
    if (i < total) P[i] = b[i & (C_ - 1)];
}
__global__ void repack_conv(const float* __restrict__ cw, float* __restrict__ out) {
    // cw: (O=256, I=256, K=7)  ->  out: (K, I, O)
    int idx = blockIdx.x * 256 + threadIdx.x;
    if (idx >= C_ * C_ * K_) return;
    int o = idx / (C_ * K_);
    int rem = idx % (C_ * K_);
    int i = rem / K_, kh = rem % K_;
    out[((long)kh * C_ + i) * C_ + o] = cw[idx];
}

// ---------------- spatial attention scores ------------------------------------
// attPre[n,u,v,s] += sum_{t in chunk, ci} qk[n,u,t,ci*6+s] * qk[n,v,t,ci*6+3+s]
__global__ __launch_bounds__(256) void att_s_partial(
    const float* __restrict__ QK,     // (N,V,T,384)
    float* __restrict__ attPre)       // (N,V,V,S) zero-init
{
    const int n = blockIdx.x;
    const int tg = blockIdx.y;        // 0..7, 8 t's each
    __shared__ float lds[V_ * 384];   // 9600 floats
    const int NOUT = V_ * V_ * S_;    // 1875
    float acc[8] = {};
    for (int ttc = 0; ttc < 8; ++ttc) {
        int t = tg * 8 + ttc;
        __syncthreads();
        for (int l = threadIdx.x; l < V_ * 384; l += 256) {
            int v = l / 384, j = l % 384;
            lds[l] = QK[(((long)n * V_ + v) * T_ + t) * 384 + j];
        }
        __syncthreads();
        int ai = 0;
        for (int o = threadIdx.x; o < NOUT; o += 256, ++ai) {
            int u = o / (V_ * S_), rem = o % (V_ * S_), v = rem / S_, s = rem % S_;
            const float* qp = &lds[u * 384 + s];
            const float* kp = &lds[v * 384 + S_ + s];
            float sum = 0.f;
            #pragma unroll 8
            for (int ci = 0; ci < CI_; ++ci) sum += qp[ci * 6] * kp[ci * 6];
            acc[ai] += sum;
        }
    }
    int ai = 0;
    for (int o = threadIdx.x; o < NOUT; o += 256, ++ai)
        atomicAdd(&attPre[(long)n * NOUT + o], acc[ai]);
}

__global__ void att_s_final(const float* __restrict__ attPre,
                            const float* __restrict__ alphas,
                            const float* __restrict__ att0,
                            float* __restrict__ attS) {
    int idx = blockIdx.x * 256 + threadIdx.x;
    if (idx >= N_ * V_ * V_ * S_) return;
    int o = idx % (V_ * V_ * S_);
    int s = o % S_;
    attS[idx] = tanhf(attPre[idx] * (1.0f / (CI_ * T_))) * alphas[s] + att0[o];
}

// ---------------- spatial mixing: P[n,v,col] += sum_u att[n,u,v,s]*T1[n,u,col] -
__global__ __launch_bounds__(256) void vmix(
    const float* __restrict__ T1,     // (N,V,TC)
    const float* __restrict__ attS,   // (N,V,V,S)
    int s, float* __restrict__ P)     // (N,V,TC)
{
    const int n = blockIdx.y;
    const int col = blockIdx.x * 256 + threadIdx.x;   // 0..TC-1
    __shared__ float a[V_ * V_];
    for (int l = threadIdx.x; l < V_ * V_; l += 256)
        a[l] = attS[((long)n * V_ * V_ + l) * S_ + s];
    __syncthreads();
    float acc[V_] = {};
    for (int u = 0; u < V_; ++u) {
        float val = T1[((long)n * V_ + u) * TC_ + col];
        #pragma unroll
        for (int v = 0; v < V_; ++v) acc[v] += a[u * V_ + v] * val;
    }
    for (int v = 0; v < V_; ++v)
        P[((long)n * V_ + v) * TC_ + col] += acc[v];
}

// ---------------- temporal attention scores -----------------------------------
__global__ __launch_bounds__(256) void att_t(
    const float* __restrict__ QKT,    // (N,T,V,512)
    const float* __restrict__ alphat_f, const float* __restrict__ alphat_b,
    float* __restrict__ attF, float* __restrict__ attB)   // (N,2,T,T) [t][q]
{
    const int n = blockIdx.z;
    const int t0 = blockIdx.y * 16, q0 = blockIdx.x * 16;
    __shared__ float Qs[16 * 256], Ks[16 * 256];
    const int tt = threadIdx.x / 16, qq = threadIdx.x % 16;
    float acc[4] = {};
    for (int v = 0; v < V_; ++v) {
        for (int h = 0; h < 2; ++h) {
            __syncthreads();
            for (int l = threadIdx.x; l < 16 * 256; l += 256) {
                int r = l >> 8, c = l & 255;
                Qs[l] = QKT[(((long)n * T_ + t0 + r) * V_ + v) * 512 + h * 256 + c];
                Ks[l] = QKT[(((long)n * T_ + q0 + r) * V_ + v) * 512 + h * 256 + c];
            }
            __syncthreads();
            #pragma unroll 8
            for (int ci = 0; ci < 32; ++ci) {
                const float* qp = &Qs[tt * 256 + ci * 8];
                const float* kp = &Ks[qq * 256 + ci * 8];
                acc[0] += qp[0] * kp[4];
                acc[1] += qp[1] * kp[5];
                acc[2] += qp[2] * kp[6];
                acc[3] += qp[3] * kp[7];
            }
        }
    }
    const int t = t0 + tt, q = q0 + qq;
    const float mf = (t >= q) ? 1.0f : 0.0f;   // bmask.T
    const float mb = (q >= t) ? 1.0f : 0.0f;   // bmask
    const float inv = 1.0f / (CI_ * V_);
    for (int s = 0; s < 2; ++s) {
        attF[(((long)n * 2 + s) * T_ + t) * T_ + q] = tanhf(acc[s]     * inv) * alphat_f[s] * mf;
        attB[(((long)n * 2 + s) * T_ + t) * T_ + q] = tanhf(acc[2 + s] * inv) * alphat_b[s] * mb;
    }
}

// ---------------- temporal mixing: P[n,q,col] += sum_t att[n,s,t,q]*T1[n,t,col] -
__global__ __launch_bounds__(256) void tmix(
    const float* __restrict__ T1,     // (N,T,VC)
    const float* __restrict__ attX,   // (N,2,T,T)
    int s, float* __restrict__ P)     // (N,T,VC)
{
    const int n = blockIdx.y;
    const int col = blockIdx.x * 64 + (threadIdx.x & 63);  // 0..VC-1
    const int ty = threadIdx.x >> 6;                       // 0..3
    __shared__ float a[T_ * T_];
    for (int l = threadIdx.x; l < T_ * T_; l += 256)
        a[l] = attX[((long)n * 2 + s) * (T_ * T_) + l];
    __syncthreads();
    float acc[16] = {};
    for (int t = 0; t < T_; ++t) {
        float val = T1[((long)n * T_ + t) * VC_ + col];
        const float* ar = &a[t * T_ + ty * 16];
        #pragma unroll
        for (int i = 0; i < 16; ++i) acc[i] += ar[i] * val;
    }
    for (int i = 0; i < 16; ++i) {
        int q = ty * 16 + i;
        P[((long)n * T_ + q) * VC_ + col] += acc[i];
    }
}

// ---------------- LayerNorm over (T,C) per (n,v): out = gelu(X + ln(P)*G+B) ----
template <bool TR>
__global__ __launch_bounds__(256) void ln_res_gelu_TC(
    const float* __restrict__ P, const float* __restrict__ X,
    const float* __restrict__ G, const float* __restrict__ B,
    float* __restrict__ Out)
{
    const int g = blockIdx.x;          // n*V+v
    const int n = g / V_, v = g % V_;
    const float* p = P + (long)g * TC_;
    const float* x = X + (long)g * TC_;
    float s = 0.f, ss = 0.f;
    for (int i = threadIdx.x; i < TC_; i += 256) { float a = p[i]; s += a; ss += a * a; }
    __shared__ float rs[4], rss[4];
    #pragma unroll
    for (int off = 32; off > 0; off >>= 1) { s += __shfl_down(s, off); ss += __shfl_down(ss, off); }
    if ((threadIdx.x & 63) == 0) { rs[threadIdx.x >> 6] = s; rss[threadIdx.x >> 6] = ss; }
    __syncthreads();
    s = rs[0] + rs[1] + rs[2] + rs[3];
    ss = rss[0] + rss[1] + rss[2] + rss[3];
    const float mean = s * (1.0f / TC_);
    const float var  = ss * (1.0f / TC_) - mean * mean;
    const float rstd = rsqrtf(var + 1e-5f);
    for (int i = threadIdx.x; i < TC_; i += 256) {
        float val = (p[i] - mean) * rstd * G[i] + B[i];
        float r = gelu_f(x[i] + val);
        if (TR) {
            int t = i >> 8, c = i & 255;
            Out[(((long)n * T_ + t) * V_ + v) * C_ + c] = r;   // write (N,T,V,C)
        } else {
            Out[(long)g * TC_ + i] = r;
        }
    }
}

// ---------------- LayerNorm over (V,C) per (n,t) ------------------------------
__global__ __launch_bounds__(256) void ln_res_gelu_VC(
    const float* __restrict__ P, const float* __restrict__ X,
    const float* __restrict__ G, const float* __restrict__ B,
    float* __restrict__ Out)
{
    const int g = blockIdx.x;          // n*T+t
    const float* p = P + (long)g * VC_;
    const float* x = X + (long)g * VC_;
    float s = 0.f, ss = 0.f;
    for (int i = threadIdx.x; i < VC_; i += 256) { float a = p[i]; s += a; ss += a * a; }
    __shared__ float rs[4], rss[4];
    #pragma unroll
    for (int off = 32; off > 0; off >>= 1) { s += __shfl_down(s, off); ss += __shfl_down(ss, off); }
    if ((threadIdx.x & 63) == 0) { rs[threadIdx.x >> 6] = s; rss[threadIdx.x >> 6] = ss; }
    __syncthreads();
    s = rs[0] + rs[1] + rs[2] + rs[3];
    ss = rss[0] + rss[1] + rss[2] + rss[3];
    const float mean = s * (1.0f / VC_);
    const float var  = ss * (1.0f / VC_) - mean * mean;
    const float rstd = rsqrtf(var + 1e-5f);
    for (int i = threadIdx.x; i < VC_; i += 256) {
        float val = (p[i] - mean) * rstd * G[i] + B[i];
        Out[(long)g * VC_ + i] = gelu_f(x[i] + val);
    }
}

// ---------------- conv(7x1 over T) + BN + residual + gelu + final transpose ---
__global__ __launch_bounds__(256) void conv_bn_gelu(
    const float* __restrict__ Z,      // (N,T,V,C)
    const float* __restrict__ Wc,     // (K,I,O) repacked
    const float* __restrict__ conv_b, const float* __restrict__ bn_g,
    const float* __restrict__ bn_b,  const float* __restrict__ bn_m,
    const float* __restrict__ bn_v,
    float* __restrict__ Out)          // (N,V,T,C)
{
    __shared__ float As[64][17];
    __shared__ float Ws[16][65];
    const int tid = threadIdx.x;
    const int tx = tid & 15, ty = tid >> 4;
    const int row0 = blockIdx.y * 64, col0 = blockIdx.x * 64;
    float acc[4][4] = {};
    for (int kh = 0; kh < K_; ++kh) {
        const int d = kh - 3;
        for (int k0 = 0; k0 < C_; k0 += 16) {
            for (int l = tid; l < 64 * 16; l += 256) {
                int r = l >> 4, c = l & 15;
                int m = row0 + r;
                int t = (m / V_) % T_;
                int t2 = t + d;
                float v = 0.0f;
                if (t2 >= 0 && t2 < T_) v = Z[(long)(m + d * V_) * C_ + k0 + c];
                As[r][c] = v;
            }
            for (int l = tid; l < 16 * 64; l += 256) {
                int r = l >> 6, c = l & 63;
                Ws[r][c] = Wc[((long)kh * C_ + k0 + r) * C_ + col0 + c];
            }
            __syncthreads();
            #pragma unroll
            for (int kk = 0; kk < 16; ++kk) {
                float a[4], w[4];
                #pragma unroll
                for (int i = 0; i < 4; ++i) a[i] = As[ty * 4 + i][kk];
                #pragma unroll
                for (int j = 0; j < 4; ++j) w[j] = Ws[kk][tx * 4 + j];
                #pragma unroll
                for (int i = 0; i < 4; ++i)
                    #pragma unroll
                    for (int j = 0; j < 4; ++j) acc[i][j] += a[i] * w[j];
            }
            __syncthreads();
        }
    }
    for (int i = 0; i < 4; ++i) {
        int m = row0 + ty * 4 + i;
        int n = m / (T_ * V_);
        int rem = m % (T_ * V_);
        int t = rem / V_, v = rem % V_;
        for (int j = 0; j < 4; ++j) {
            int o = col0 + tx * 4 + j;
            float cv = acc[i][j] + conv_b[o];
            float bn = (cv - bn_m[o]) * rsqrtf(bn_v[o] + 1e-5f) * bn_g[o] + bn_b[o];
            float res = Z[(long)m * C_ + o];
            Out[(((long)n * V_ + v) * T_ + t) * C_ + o] = gelu_f(res + bn);
        }
    }
}

// ==============================================================================
extern "C" void kernel_launch(void* const* d_in, const int* in_sizes, int n_in,
                              void* d_out, int out_size, void* d_ws, size_t ws_size,
                              hipStream_t stream)
{
    const float* x        = (const float*)d_in[0];
    const float* Wqk_s    = (const float*)d_in[1];
    const float* bqk_s    = (const float*)d_in[2];
    const float* alphas   = (const float*)d_in[3];
    const float* att0s    = (const float*)d_in[4];
    const float* Wo_s     = (const float*)d_in[5];
    const float* bo_s     = (const float*)d_in[6];
    const float* g_os     = (const float*)d_in[7];
    const float* b_os     = (const float*)d_in[8];
    const float* Wff_s    = (const float*)d_in[9];
    const float* bff_s    = (const float*)d_in[10];
    const float* g_ffs    = (const float*)d_in[11];
    const float* b_ffs    = (const float*)d_in[12];
    const float* Wqk_t    = (const float*)d_in[13];
    const float* bqk_t    = (const float*)d_in[14];
    const float* alphat_f = (const float*)d_in[15];
    const float* alphat_b = (const float*)d_in[16];
    const float* Wo_t     = (const float*)d_in[17];
    const float* bo_t     = (const float*)d_in[18];
    const float* g_ot     = (const float*)d_in[19];
    const float* b_ot     = (const float*)d_in[20];
    const float* Wff_t    = (const float*)d_in[21];
    const float* bff_t    = (const float*)d_in[22];
    const float* g_fft    = (const float*)d_in[23];
    const float* b_fft    = (const float*)d_in[24];
    const float* conv_w   = (const float*)d_in[25];
    const float* conv_b   = (const float*)d_in[26];
    const float* bn_g     = (const float*)d_in[27];
    const float* bn_b     = (const float*)d_in[28];
    const float* bn_m     = (const float*)d_in[29];
    const float* bn_v     = (const float*)d_in[30];

    float* ws = (float*)d_ws;
    float* R1 = ws;                         // 26,214,400 f (qk / qkt / Z)
    float* R2 = R1 + (long)N_*T_*V_*512;    // 13,107,200 f (P accum)
    float* R3 = R2 + TOT_;                  // 13,107,200 f (T1 / Y / Z2)
    float* RA = R3 + TOT_;
    float* attPre = RA;                               // 60,000
    float* attS   = attPre + N_*V_*V_*S_;             // 60,000
    float* attF   = attS   + N_*V_*V_*S_;             // 262,144
    float* attB   = attF   + (long)N_*2*T_*T_;        // 262,144
    float* convW  = attB   + (long)N_*2*T_*T_;        // 458,752
    float* YT = (float*)d_out;              // y^T (N,T,V,C); overwritten at the end

    const int TOT_I = (int)TOT_;

    // ---- Stage 1: spatial ----
    // qk = x @ Wqk_s + bqk_s
    gemm_bias<<<dim3(384/64, M_/64), 256, 0, stream>>>(x, C_, Wqk_s, 2*S_*CI_, bqk_s, R1, M_, 2*S_*CI_, C_);
    // att_s
    zero_f32<<<(N_*V_*V_*S_ + 255)/256, 256, 0, stream>>>(attPre, N_*V_*V_*S_);
    att_s_partial<<<dim3(N_, 8), 256, 0, stream>>>(R1, attPre);
    att_s_final<<<(N_*V_*V_*S_ + 255)/256, 256, 0, stream>>>(attPre, alphas, att0s, attS);
    // P = bo_s + sum_s attmix_s(x @ Wo_block_s)
    bcast_bias<<<(TOT_I + 255)/256, 256, 0, stream>>>(bo_s, R2, TOT_I);
    for (int s = 0; s < S_; ++s) {
        gemm_bias<<<dim3(C_/64, M_/64), 256, 0, stream>>>(x, C_, Wo_s + s*C_, S_*C_, nullptr, R3, M_, C_, C_);
        vmix<<<dim3(TC_/256, N_), 256, 0, stream>>>(R3, attS, s, R2);
    }
    // Y = gelu(x + ln(P))
    ln_res_gelu_TC<false><<<N_*V_, 256, 0, stream>>>(R2, x, g_os, b_os, R3);
    // P2 = Y @ Wff_s + bff_s ; YT = gelu(x + ln(P2)) transposed to (N,T,V,C)
    gemm_bias<<<dim3(C_/64, M_/64), 256, 0, stream>>>(R3, C_, Wff_s, C_, bff_s, R2, M_, C_, C_);
    ln_res_gelu_TC<true><<<N_*V_, 256, 0, stream>>>(R2, x, g_ffs, b_ffs, YT);

    // ---- Stage 2: temporal ----
    gemm_bias<<<dim3(512/64, M_/64), 256, 0, stream>>>(YT, C_, Wqk_t, 4*ST_*CI_, bqk_t, R1, M_, 4*ST_*CI_, C_);
    att_t<<<dim3(4, 4, N_), 256, 0, stream>>>(R1, alphat_f, alphat_b, attF, attB);
    bcast_bias<<<(TOT_I + 255)/256, 256, 0, stream>>>(bo_t, R2, TOT_I);
    for (int s = 0; s < ST_; ++s) {
        // forward block: Wo_t rows c*ST+s
        gemm_bias<<<dim3(C_/64, M_/64), 256, 0, stream>>>(YT, C_, Wo_t + s*C_, ST_*C_, nullptr, R3, M_, C_, C_);
        tmix<<<dim3(VC_/64, N_), 256, 0, stream>>>(R3, attF, s, R2);
        // backward block: Wo_t rows ST*C + c*ST+s
        gemm_bias<<<dim3(C_/64, M_/64), 256, 0, stream>>>(YT, C_, Wo_t + (long)ST_*C_*C_ + s*C_, ST_*C_, nullptr, R3, M_, C_, C_);
        tmix<<<dim3(VC_/64, N_), 256, 0, stream>>>(R3, attB, s, R2);
    }
    // Z = gelu(yT + ln(P))
    ln_res_gelu_VC<<<N_*T_, 256, 0, stream>>>(R2, YT, g_ot, b_ot, R1);
    // P2 = Z @ Wff_t + bff_t ; Z2 = gelu(yT + ln(P2))
    gemm_bias<<<dim3(C_/64, M_/64), 256, 0, stream>>>(R1, C_, Wff_t, C_, bff_t, R2, M_, C_, C_);
    ln_res_gelu_VC<<<N_*T_, 256, 0, stream>>>(R2, YT, g_fft, b_fft, R3);

    // ---- Stage 3: conv + BN + gelu + transpose ----
    repack_conv<<<(C_*C_*K_ + 255)/256, 256, 0, stream>>>(conv_w, convW);
    conv_bn_gelu<<<dim3(C_/64, M_/64), 256, 0, stream>>>(R3, convW, conv_b, bn_g, bn_b, bn_m, bn_v, (float*)d_out);
}